// Round 1
// baseline (110.580 us; speedup 1.0000x reference)
//
#include <hip/hip_runtime.h>

// NetVLAD: features (32,32,32,128) f32, centers (32,64,128) f32 -> out (32, 8192) f32
// score_k = 2*f.c_k - |c_k|^2  (softmax-invariant shift; drops |f|^2)
// vlad[b,k,d] = sum_ij sim*f_d - (sum_ij sim)*c_kd ; out = vlad / ||vlad||_global

#define NB    32
#define NIJ   1024
#define ND    128
#define NK    64
#define SPLIT 16
#define PPB   64   // pixels per block  (NIJ/SPLIT)
#define PPI   8    // pixels per iteration
#define NIT   8    // PPB/PPI

__global__ __launch_bounds__(256, 2)
void netvlad_main(const float* __restrict__ feat,
                  const float* __restrict__ cent,
                  float* __restrict__ partial) {
    // centers staged as float4 with XOR swizzle: slot = k*32 + (d4 ^ (k&31))
    __shared__ float4 centLDS[NK * 32];
    __shared__ float  c2[NK];
    __shared__ float4 fLDS[PPI * 32];      // 8 pixels x 128 floats
    __shared__ float  simbuf[PPI * NK];    // 8 pixels x 64 sims

    const int tid = threadIdx.x;
    const int bs  = blockIdx.x;
    const int b   = bs >> 4;     // /SPLIT
    const int s   = bs & 15;
    const int n0  = s * PPB;

    // ---- stage centers (coalesced global, swizzled LDS) ----
    const float4* cent4 = reinterpret_cast<const float4*>(cent) + (size_t)b * (NK * ND / 4);
    #pragma unroll
    for (int it = 0; it < 8; ++it) {
        int g  = it * 256 + tid;
        int k  = g >> 5;
        int d4 = g & 31;
        centLDS[k * 32 + (d4 ^ (k & 31))] = cent4[g];
    }
    __syncthreads();

    // ---- |c_k|^2 ----
    if (tid < NK) {
        int k = tid;
        float a = 0.f;
        #pragma unroll
        for (int j = 0; j < 32; ++j) {
            float4 c4 = centLDS[k * 32 + (j ^ (k & 31))];
            a += c4.x * c4.x + c4.y * c4.y + c4.z * c4.z + c4.w * c4.w;
        }
        c2[k] = a;
    }
    __syncthreads();

    const float4* feat4 = reinterpret_cast<const float4*>(feat) + (size_t)b * (NIJ * ND / 4);

    const int kg   = tid >> 5;   // 0..7  (owns k = kg*8 .. kg*8+7)
    const int dg   = tid & 31;   // 0..31 (owns d4 = dg)
    const int w    = tid >> 6;   // wave 0..3
    const int lane = tid & 63;   // k index in dot phase
    const int swz  = lane & 31;

    float4 acc[8];
    float  ssum[8];
    #pragma unroll
    for (int i = 0; i < 8; ++i) { acc[i] = make_float4(0.f, 0.f, 0.f, 0.f); ssum[i] = 0.f; }

    for (int it = 0; it < NIT; ++it) {
        // ---- stage 8 pixels (2 KB contiguous, coalesced) ----
        fLDS[tid] = feat4[(size_t)(n0 + it * PPI) * 32 + tid];
        __syncthreads();

        // ---- dot phase: wave w handles pixels 2w, 2w+1; lane = k ----
        float4 a0 = make_float4(0.f, 0.f, 0.f, 0.f);
        float4 a1 = make_float4(0.f, 0.f, 0.f, 0.f);
        const float4* f0 = &fLDS[(2 * w + 0) * 32];
        const float4* f1 = &fLDS[(2 * w + 1) * 32];
        #pragma unroll
        for (int j = 0; j < 32; ++j) {
            float4 c4 = centLDS[lane * 32 + (j ^ swz)];   // conflict-free via swizzle
            float4 u  = f0[j];                            // broadcast
            float4 v  = f1[j];                            // broadcast
            a0.x += c4.x * u.x; a0.y += c4.y * u.y; a0.z += c4.z * u.z; a0.w += c4.w * u.w;
            a1.x += c4.x * v.x; a1.y += c4.y * v.y; a1.z += c4.z * v.z; a1.w += c4.w * v.w;
        }
        float s0 = 2.f * (a0.x + a0.y + a0.z + a0.w) - c2[lane];
        float s1 = 2.f * (a1.x + a1.y + a1.z + a1.w) - c2[lane];

        // ---- in-wave softmax over 64 lanes ----
        float m0 = s0, m1 = s1;
        #pragma unroll
        for (int off = 32; off > 0; off >>= 1) {
            m0 = fmaxf(m0, __shfl_xor(m0, off));
            m1 = fmaxf(m1, __shfl_xor(m1, off));
        }
        float e0 = __expf(s0 - m0), e1 = __expf(s1 - m1);
        float t0 = e0, t1 = e1;
        #pragma unroll
        for (int off = 32; off > 0; off >>= 1) {
            t0 += __shfl_xor(t0, off);
            t1 += __shfl_xor(t1, off);
        }
        simbuf[(2 * w + 0) * NK + lane] = e0 / t0;
        simbuf[(2 * w + 1) * NK + lane] = e1 / t1;
        __syncthreads();

        // ---- accumulate: thread owns 8 k x 4 d, registers only ----
        #pragma unroll
        for (int p = 0; p < PPI; ++p) {
            float4 fv = fLDS[p * 32 + dg];
            const float4* sp4 = reinterpret_cast<const float4*>(&simbuf[p * NK + kg * 8]);
            float4 sa = sp4[0], sb = sp4[1];
            float sv[8] = { sa.x, sa.y, sa.z, sa.w, sb.x, sb.y, sb.z, sb.w };
            #pragma unroll
            for (int i = 0; i < 8; ++i) {
                acc[i].x += sv[i] * fv.x;
                acc[i].y += sv[i] * fv.y;
                acc[i].z += sv[i] * fv.z;
                acc[i].w += sv[i] * fv.w;
                ssum[i]  += sv[i];
            }
        }
        __syncthreads();
    }

    // ---- epilogue: partial[bs][k][d] = acc - ssum*c ----
    float4* out4 = reinterpret_cast<float4*>(partial) + (size_t)bs * (NK * ND / 4);
    #pragma unroll
    for (int i = 0; i < 8; ++i) {
        int k = kg * 8 + i;
        float4 c4 = centLDS[k * 32 + (dg ^ (k & 31))];
        float4 o;
        o.x = acc[i].x - ssum[i] * c4.x;
        o.y = acc[i].y - ssum[i] * c4.y;
        o.z = acc[i].z - ssum[i] * c4.z;
        o.w = acc[i].w - ssum[i] * c4.w;
        out4[k * 32 + dg] = o;
    }
}

__global__ __launch_bounds__(256)
void netvlad_reduce(const float* __restrict__ partial,
                    float* __restrict__ vlad,
                    float* __restrict__ sumsq) {
    int idx = blockIdx.x * 256 + threadIdx.x;   // float4 id, 0..65535
    int b   = idx >> 11;                        // 2048 float4 per batch
    int r   = idx & 2047;
    const float4* p4 = reinterpret_cast<const float4*>(partial);
    float4 a = make_float4(0.f, 0.f, 0.f, 0.f);
    #pragma unroll
    for (int s = 0; s < SPLIT; ++s) {
        float4 v = p4[(size_t)(b * SPLIT + s) * 2048 + r];
        a.x += v.x; a.y += v.y; a.z += v.z; a.w += v.w;
    }
    reinterpret_cast<float4*>(vlad)[idx] = a;
    float sq = a.x * a.x + a.y * a.y + a.z * a.z + a.w * a.w;
    #pragma unroll
    for (int off = 32; off > 0; off >>= 1) sq += __shfl_xor(sq, off);
    if ((threadIdx.x & 63) == 0) atomicAdd(sumsq, sq);
}

__global__ __launch_bounds__(256)
void netvlad_norm(const float* __restrict__ vlad,
                  const float* __restrict__ sumsq,
                  float* __restrict__ out) {
    int idx = blockIdx.x * 256 + threadIdx.x;   // float4 id
    float n   = sqrtf(fmaxf(*sumsq, 1e-12f));
    float inv = 1.0f / n;
    float4 v = reinterpret_cast<const float4*>(vlad)[idx];
    float4 o;
    o.x = v.x * inv; o.y = v.y * inv; o.z = v.z * inv; o.w = v.w * inv;
    reinterpret_cast<float4*>(out)[idx] = o;
}

extern "C" void kernel_launch(void* const* d_in, const int* in_sizes, int n_in,
                              void* d_out, int out_size, void* d_ws, size_t ws_size,
                              hipStream_t stream) {
    const float* feat = (const float*)d_in[0];   // (32,32,32,128)
    const float* cent = (const float*)d_in[1];   // (32,64,128)
    float* out = (float*)d_out;                  // (32,8192)

    char* ws = (char*)d_ws;
    const size_t partial_bytes = (size_t)NB * SPLIT * NK * ND * sizeof(float); // 16 MB
    const size_t vlad_bytes    = (size_t)NB * NK * ND * sizeof(float);         // 1 MB
    float* partial = (float*)ws;
    float* vlad    = (float*)(ws + partial_bytes);
    float* sumsq   = (float*)(ws + partial_bytes + vlad_bytes);

    hipMemsetAsync(sumsq, 0, sizeof(float), stream);
    netvlad_main  <<<NB * SPLIT, 256, 0, stream>>>(feat, cent, partial);
    netvlad_reduce<<<256, 256, 0, stream>>>(partial, vlad, sumsq);
    netvlad_norm  <<<256, 256, 0, stream>>>(vlad, sumsq, out);
}

// Round 2
// 85.556 us; speedup vs baseline: 1.2925x; 1.2925x over previous
//
#include <hip/hip_runtime.h>

// NetVLAD MI355X: features (32,32,32,128) f32, centers (32,64,128) f32 -> out (32,8192) f32
// Phase 1: scores = 2*F.C^T - |c|^2 via split-bf16 MFMA (16x16x32, 3 terms: AhBh+AhBl+AlBh)
// Softmax over k=64 via 16-lane shfl groups (C-layout: col=lane&15, row=(lane>>4)*4+reg)
// Phase 2: vlad partial = sim^T.F via VALU register accumulators (8k x 4d per thread)
// Reduce: sum 16 splits, per-block sq partials (NO same-address atomic storm)
// Norm: redundant per-wave reduce of 256 sq partials, scale.

#define NB    32
#define NIJ   1024
#define ND    128
#define NK    64
#define SPLIT 16
#define PPB   64

typedef short short8 __attribute__((ext_vector_type(8)));
typedef float f32x4  __attribute__((ext_vector_type(4)));

__device__ __forceinline__ float bf2f(unsigned short u) {
    return __uint_as_float(((unsigned)u) << 16);
}
__device__ __forceinline__ unsigned short f2bf(float f) {
    unsigned u = __float_as_uint(f);
    return (unsigned short)((u + 0x7fffu + ((u >> 16) & 1u)) >> 16);
}

// LDS map (81920 B = 80 KiB exactly -> 2 blocks/CU):
// [    0,16384) centHi bf16[64][128], 8B-unit idx: k*32 + (d4 ^ ((k&7)<<1))
// [16384,32768) centLo same layout
// [32768,65536) fLDS f32[64][128], float4 idx: p*32 + (d4 ^ (p&7))
// [65536,81920) simLDS f32[64][64] slot-swizzled; first 64 floats = c2[] pre-phase
__global__ __launch_bounds__(256, 2)
void netvlad_main(const float* __restrict__ feat,
                  const float* __restrict__ cent,
                  float* __restrict__ partial)
{
    __shared__ __align__(16) char smem[81920];
    ushort4* centHi = (ushort4*)smem;
    ushort4* centLo = (ushort4*)(smem + 16384);
    float4*  fL     = (float4*)(smem + 32768);
    float*   simf   = (float*)(smem + 65536);
    float4*  sim4   = (float4*)(smem + 65536);

    const int tid = threadIdx.x;
    const int bs  = blockIdx.x;
    const int b   = bs >> 4;
    const int n0  = (bs & 15) * PPB;

    const float4* cent4 = (const float4*)cent + (size_t)b * (NK * ND / 4);
    const float4* feat4 = (const float4*)feat + ((size_t)b * NIJ + n0) * (ND / 4);

    // ---- stage centers as bf16 hi/lo (swizzled) ----
    #pragma unroll
    for (int it = 0; it < 8; ++it) {
        int g  = it * 256 + tid;
        int k  = g >> 5;
        int d4 = g & 31;
        float4 v = cent4[g];
        ushort4 h, l;
        h.x = f2bf(v.x); l.x = f2bf(v.x - bf2f(h.x));
        h.y = f2bf(v.y); l.y = f2bf(v.y - bf2f(h.y));
        h.z = f2bf(v.z); l.z = f2bf(v.z - bf2f(h.z));
        h.w = f2bf(v.w); l.w = f2bf(v.w - bf2f(h.w));
        int idx = k * 32 + (d4 ^ ((k & 7) << 1));
        centHi[idx] = h; centLo[idx] = l;
    }
    // ---- stage F f32 (swizzled) ----
    #pragma unroll
    for (int it = 0; it < 8; ++it) {
        int g  = it * 256 + tid;
        int p  = g >> 5;
        int d4 = g & 31;
        fL[p * 32 + (d4 ^ (p & 7))] = feat4[g];
    }
    __syncthreads();

    // ---- c2[k] into simf[0..63] ----
    if (tid < NK) {
        int k = tid;
        float a = 0.f;
        #pragma unroll
        for (int d4 = 0; d4 < 32; ++d4) {
            int idx = k * 32 + (d4 ^ ((k & 7) << 1));
            ushort4 h = centHi[idx], l = centLo[idx];
            float c0 = bf2f(h.x) + bf2f(l.x);
            float c1 = bf2f(h.y) + bf2f(l.y);
            float c2v = bf2f(h.z) + bf2f(l.z);
            float c3 = bf2f(h.w) + bf2f(l.w);
            a += c0 * c0 + c1 * c1 + c2v * c2v + c3 * c3;
        }
        simf[k] = a;
    }
    __syncthreads();

    const int w  = tid >> 6;
    const int l  = tid & 63;
    const int lr = l & 15;
    const int lg = l >> 4;

    float c2r[4];
    #pragma unroll
    for (int nt = 0; nt < 4; ++nt) c2r[nt] = simf[nt * 16 + lr];
    __syncthreads();   // c2 reads done before sim overwrites

    // ---- phase 1: MFMA scores (wave w owns pixels 16w..16w+15, all 64 clusters) ----
    f32x4 acc[4];
    #pragma unroll
    for (int nt = 0; nt < 4; ++nt) acc[nt] = (f32x4){0.f, 0.f, 0.f, 0.f};

    const int prow = 16 * w + lr;
    #pragma unroll
    for (int kt = 0; kt < 4; ++kt) {
        float4 fa = fL[prow * 32 + ((kt * 8 + 2 * lg + 0) ^ (prow & 7))];
        float4 fb = fL[prow * 32 + ((kt * 8 + 2 * lg + 1) ^ (prow & 7))];
        float fv[8] = { fa.x, fa.y, fa.z, fa.w, fb.x, fb.y, fb.z, fb.w };
        short8 ah, al;
        #pragma unroll
        for (int j = 0; j < 8; ++j) {
            unsigned short h = f2bf(fv[j]);
            ah[j] = (short)h;
            al[j] = (short)f2bf(fv[j] - bf2f(h));
        }
        #pragma unroll
        for (int nt = 0; nt < 4; ++nt) {
            int c  = nt * 16 + lr;
            int ch = c * 16 + ((kt * 4 + lg) ^ (c & 7));  // 16B chunk index
            short8 bh = *(const short8*)(smem + ch * 16);
            short8 bl = *(const short8*)(smem + 16384 + ch * 16);
            acc[nt] = __builtin_amdgcn_mfma_f32_16x16x32_bf16(ah, bh, acc[nt], 0, 0, 0);
            acc[nt] = __builtin_amdgcn_mfma_f32_16x16x32_bf16(ah, bl, acc[nt], 0, 0, 0);
            acc[nt] = __builtin_amdgcn_mfma_f32_16x16x32_bf16(al, bh, acc[nt], 0, 0, 0);
        }
    }

    // ---- softmax per output row, write sim to LDS (swizzled slots) ----
    #pragma unroll
    for (int r = 0; r < 4; ++r) {
        float s[4];
        #pragma unroll
        for (int nt = 0; nt < 4; ++nt) s[nt] = 2.f * acc[nt][r] - c2r[nt];
        float m = fmaxf(fmaxf(s[0], s[1]), fmaxf(s[2], s[3]));
        #pragma unroll
        for (int o = 8; o >= 1; o >>= 1) m = fmaxf(m, __shfl_xor(m, o));
        float e[4], t = 0.f;
        #pragma unroll
        for (int nt = 0; nt < 4; ++nt) { e[nt] = __expf(s[nt] - m); t += e[nt]; }
        #pragma unroll
        for (int o = 8; o >= 1; o >>= 1) t += __shfl_xor(t, o);
        float inv = __builtin_amdgcn_rcpf(t);
        int p = 16 * w + 4 * lg + r;
        #pragma unroll
        for (int nt = 0; nt < 4; ++nt) {
            int k  = nt * 16 + lr;
            int kc = k >> 2;
            int slot = (((kc >> 2) ^ ((p >> 2) & 3)) << 2) | ((kc & 3) ^ (p & 3));
            simf[p * 64 + slot * 4 + (k & 3)] = e[nt] * inv;
        }
    }
    __syncthreads();

    // ---- phase 2: VALU accumulate (thread owns 8 k x 4 d) ----
    const int kg = tid >> 5;
    const int dg = tid & 31;
    float4 a2[8];
    float  ss[8];
    #pragma unroll
    for (int i = 0; i < 8; ++i) { a2[i] = make_float4(0.f, 0.f, 0.f, 0.f); ss[i] = 0.f; }

    const int kcq = kg >> 1;           // (2kg)>>2 == (2kg+1)>>2
    const int kl0 = 2 * (kg & 1);      // (2kg)&3
    #pragma unroll 4
    for (int p = 0; p < 64; ++p) {
        float4 fv = fL[p * 32 + (dg ^ (p & 7))];
        int pz2 = (p >> 2) & 3, pz = p & 3;
        int s0 = (((kcq ^ pz2) << 2) | ((kl0 + 0) ^ pz));
        int s1 = (((kcq ^ pz2) << 2) | ((kl0 + 1) ^ pz));
        float4 sa = sim4[p * 16 + s0];
        float4 sb = sim4[p * 16 + s1];
        float sv[8] = { sa.x, sa.y, sa.z, sa.w, sb.x, sb.y, sb.z, sb.w };
        #pragma unroll
        for (int i = 0; i < 8; ++i) {
            a2[i].x += sv[i] * fv.x;
            a2[i].y += sv[i] * fv.y;
            a2[i].z += sv[i] * fv.z;
            a2[i].w += sv[i] * fv.w;
            ss[i]   += sv[i];
        }
    }

    // ---- epilogue: partial[bs][k][d] = a2 - ss * c ----
    float4* out4 = (float4*)partial + (size_t)bs * (NK * ND / 4);
    #pragma unroll
    for (int i = 0; i < 8; ++i) {
        int k   = kg * 8 + i;
        int idx = k * 32 + (dg ^ ((k & 7) << 1));
        ushort4 h = centHi[idx], lo = centLo[idx];
        float4 o;
        o.x = a2[i].x - ss[i] * (bf2f(h.x) + bf2f(lo.x));
        o.y = a2[i].y - ss[i] * (bf2f(h.y) + bf2f(lo.y));
        o.z = a2[i].z - ss[i] * (bf2f(h.z) + bf2f(lo.z));
        o.w = a2[i].w - ss[i] * (bf2f(h.w) + bf2f(lo.w));
        out4[k * 32 + dg] = o;
    }
}

__global__ __launch_bounds__(256)
void netvlad_reduce(const float* __restrict__ partial,
                    float* __restrict__ vlad,
                    float* __restrict__ sqpart) {
    __shared__ float wsum[4];
    int idx = blockIdx.x * 256 + threadIdx.x;   // float4 id
    int b   = idx >> 11;
    int r   = idx & 2047;
    const float4* p4 = (const float4*)partial;
    float4 a = make_float4(0.f, 0.f, 0.f, 0.f);
    #pragma unroll
    for (int s = 0; s < SPLIT; ++s) {
        float4 v = p4[((size_t)(b * SPLIT + s)) * 2048 + r];
        a.x += v.x; a.y += v.y; a.z += v.z; a.w += v.w;
    }
    ((float4*)vlad)[idx] = a;
    float sq = a.x * a.x + a.y * a.y + a.z * a.z + a.w * a.w;
    #pragma unroll
    for (int o = 32; o >= 1; o >>= 1) sq += __shfl_xor(sq, o);
    if ((threadIdx.x & 63) == 0) wsum[threadIdx.x >> 6] = sq;
    __syncthreads();
    if (threadIdx.x == 0) sqpart[blockIdx.x] = wsum[0] + wsum[1] + wsum[2] + wsum[3];
}

__global__ __launch_bounds__(256)
void netvlad_norm(const float* __restrict__ vlad,
                  const float* __restrict__ sqpart,
                  float* __restrict__ out) {
    // every wave redundantly reduces the 256 block partials (64 float4s, L2-hit)
    const float4* sq4 = (const float4*)sqpart;
    float4 v = sq4[threadIdx.x & 63];
    float t = v.x + v.y + v.z + v.w;
    #pragma unroll
    for (int o = 32; o >= 1; o >>= 1) t += __shfl_xor(t, o);
    float inv = __builtin_amdgcn_rcpf(sqrtf(fmaxf(t, 1e-12f)));
    int idx = blockIdx.x * 256 + threadIdx.x;
    float4 x = ((const float4*)vlad)[idx];
    float4 o4 = make_float4(x.x * inv, x.y * inv, x.z * inv, x.w * inv);
    ((float4*)out)[idx] = o4;
}

extern "C" void kernel_launch(void* const* d_in, const int* in_sizes, int n_in,
                              void* d_out, int out_size, void* d_ws, size_t ws_size,
                              hipStream_t stream) {
    const float* feat = (const float*)d_in[0];   // (32,32,32,128)
    const float* cent = (const float*)d_in[1];   // (32,64,128)
    float* out = (float*)d_out;                  // (32,8192)

    char* ws = (char*)d_ws;
    const size_t partial_bytes = (size_t)NB * SPLIT * NK * ND * sizeof(float); // 16 MB
    const size_t vlad_bytes    = (size_t)NB * NK * ND * sizeof(float);         // 1 MB
    float* partial = (float*)ws;
    float* vlad    = (float*)(ws + partial_bytes);
    float* sqpart  = (float*)(ws + partial_bytes + vlad_bytes);               // 256 floats

    netvlad_main  <<<NB * SPLIT, 256, 0, stream>>>(feat, cent, partial);
    netvlad_reduce<<<256, 256, 0, stream>>>(partial, vlad, sqpart);
    netvlad_norm  <<<256, 256, 0, stream>>>(vlad, sqpart, out);
}

// Round 3
// 79.234 us; speedup vs baseline: 1.3956x; 1.0798x over previous
//
#include <hip/hip_runtime.h>

// NetVLAD MI355X v3: both GEMM phases on MFMA.
// Phase 1: scores = 2*F.C^T - |c|^2, split-bf16 MFMA 16x16x32 (3 terms) [verified r2]
// Phase 2: vlad_pos[k,d] = sum_p sim[p,k]*F[p,d] via MFMA with
//          A = simT[k][p] (bf16, written at softmax), B = F_T[d][p] (bf16, written at staging),
//          both chunk-XOR swizzled (<=2-way bank conflicts on all read+write patterns).
// -ssum*c folded into reduce kernel (reads centers coalesced from global).

#define NB    32
#define SPLIT 16

typedef short short8 __attribute__((ext_vector_type(8)));
typedef float f32x4  __attribute__((ext_vector_type(4)));

__device__ __forceinline__ float bf2f(unsigned short u) {
    return __uint_as_float(((unsigned)u) << 16);
}
__device__ __forceinline__ unsigned short f2bf(float f) {
    unsigned u = __float_as_uint(f);
    return (unsigned short)((u + 0x7fffu + ((u >> 16) & 1u)) >> 16);
}
__device__ __forceinline__ int swz3(int x) { return (x ^ (x >> 3)) & 7; }

// LDS map (58,624 B -> 2 blocks/CU):
// [    0,16384) centHi bf16[64][128], ushort4 idx: k*32 + (d4 ^ ((k&7)<<1))
// [16384,32768) centLo same layout
// [32768,49152) F_T  bf16[128][64], elem: d*64 + ((p>>3 ^ swz3(d))<<3) + (p&7)
// [49152,57344) simT bf16[64][64],  elem: k*64 + ((p>>3 ^ swz3(k))<<3) + (p&7)
// [57344,57600) c2 f32[64]
// [57600,58624) ssumW f32[4][64]
__global__ __launch_bounds__(256, 2)
void netvlad_main(const float* __restrict__ feat,
                  const float* __restrict__ cent,
                  float* __restrict__ partial,
                  float* __restrict__ ssumG)
{
    __shared__ __align__(16) char smem[58624];
    ushort4*        centHi = (ushort4*)smem;
    ushort4*        centLo = (ushort4*)(smem + 16384);
    unsigned short* FT     = (unsigned short*)(smem + 32768);
    unsigned short* ST     = (unsigned short*)(smem + 49152);
    float*          c2L    = (float*)(smem + 57344);
    float*          ssumW  = (float*)(smem + 57600);

    const int tid = threadIdx.x;
    const int bs  = blockIdx.x;
    const int b   = bs >> 4;
    const int n0  = (bs & 15) * 64;

    const float4* cent4 = (const float4*)cent + (size_t)b * 2048;
    const float4* feat4 = (const float4*)feat + ((size_t)b * 1024 + n0) * 32;

    // ---- stage centers as bf16 hi/lo (swizzled, verified r2) ----
    #pragma unroll
    for (int it = 0; it < 8; ++it) {
        int g  = it * 256 + tid;
        int k  = g >> 5;
        int d4 = g & 31;
        float4 v = cent4[g];
        ushort4 h, l;
        h.x = f2bf(v.x); l.x = f2bf(v.x - bf2f(h.x));
        h.y = f2bf(v.y); l.y = f2bf(v.y - bf2f(h.y));
        h.z = f2bf(v.z); l.z = f2bf(v.z - bf2f(h.z));
        h.w = f2bf(v.w); l.w = f2bf(v.w - bf2f(h.w));
        int idx = k * 32 + (d4 ^ ((k & 7) << 1));
        centHi[idx] = h; centLo[idx] = l;
    }

    const int w    = tid >> 6;
    const int lane = tid & 63;
    const int lr   = lane & 15;
    const int lg   = lane >> 4;
    const int prow = 16 * w + lr;       // this lane's F row (pixel within block)

    // ---- A-frags: global -> registers (fp32), split to bf16 hi/lo; scatter F_T (hi) ----
    short8 ah[4], al[4];
    #pragma unroll
    for (int kt = 0; kt < 4; ++kt) {
        float4 fa = feat4[prow * 32 + kt * 8 + 2 * lg + 0];
        float4 fb = feat4[prow * 32 + kt * 8 + 2 * lg + 1];
        float fv[8] = { fa.x, fa.y, fa.z, fa.w, fb.x, fb.y, fb.z, fb.w };
        #pragma unroll
        for (int j = 0; j < 8; ++j) {
            unsigned short h = f2bf(fv[j]);
            ah[kt][j] = (short)h;
            al[kt][j] = (short)f2bf(fv[j] - bf2f(h));
            int d = kt * 32 + 8 * lg + j;
            FT[d * 64 + ((((prow >> 3) ^ swz3(d))) << 3) + (prow & 7)] = h;
        }
    }
    __syncthreads();

    // ---- c2[k] ----
    if (tid < 64) {
        int k = tid;
        float a = 0.f;
        #pragma unroll
        for (int d4 = 0; d4 < 32; ++d4) {
            int idx = k * 32 + (d4 ^ ((k & 7) << 1));
            ushort4 h = centHi[idx], l = centLo[idx];
            float c0 = bf2f(h.x) + bf2f(l.x);
            float c1 = bf2f(h.y) + bf2f(l.y);
            float c2v = bf2f(h.z) + bf2f(l.z);
            float c3 = bf2f(h.w) + bf2f(l.w);
            a += c0 * c0 + c1 * c1 + c2v * c2v + c3 * c3;
        }
        c2L[k] = a;
    }
    __syncthreads();

    float c2r[4];
    #pragma unroll
    for (int nt = 0; nt < 4; ++nt) c2r[nt] = c2L[nt * 16 + lr];

    // ---- phase 1: scores via split-bf16 MFMA ----
    f32x4 acc[4];
    #pragma unroll
    for (int nt = 0; nt < 4; ++nt) acc[nt] = (f32x4){0.f, 0.f, 0.f, 0.f};
    #pragma unroll
    for (int kt = 0; kt < 4; ++kt) {
        #pragma unroll
        for (int nt = 0; nt < 4; ++nt) {
            int c  = nt * 16 + lr;
            int ch = c * 16 + ((kt * 4 + lg) ^ (c & 7));
            short8 bh = *(const short8*)(smem + ch * 16);
            short8 bl = *(const short8*)(smem + 16384 + ch * 16);
            acc[nt] = __builtin_amdgcn_mfma_f32_16x16x32_bf16(ah[kt], bh, acc[nt], 0, 0, 0);
            acc[nt] = __builtin_amdgcn_mfma_f32_16x16x32_bf16(ah[kt], bl, acc[nt], 0, 0, 0);
            acc[nt] = __builtin_amdgcn_mfma_f32_16x16x32_bf16(al[kt], bh, acc[nt], 0, 0, 0);
        }
    }

    // ---- softmax; write simT bf16; accumulate ssum partials ----
    float ssp[4] = {0.f, 0.f, 0.f, 0.f};
    #pragma unroll
    for (int r = 0; r < 4; ++r) {
        float s[4];
        #pragma unroll
        for (int nt = 0; nt < 4; ++nt) s[nt] = 2.f * acc[nt][r] - c2r[nt];
        float m = fmaxf(fmaxf(s[0], s[1]), fmaxf(s[2], s[3]));
        #pragma unroll
        for (int o = 8; o >= 1; o >>= 1) m = fmaxf(m, __shfl_xor(m, o));
        float e[4], t = 0.f;
        #pragma unroll
        for (int nt = 0; nt < 4; ++nt) { e[nt] = __expf(s[nt] - m); t += e[nt]; }
        #pragma unroll
        for (int o = 8; o >= 1; o >>= 1) t += __shfl_xor(t, o);
        float inv = __builtin_amdgcn_rcpf(t);
        int p = 16 * w + 4 * lg + r;
        #pragma unroll
        for (int nt = 0; nt < 4; ++nt) {
            int k = nt * 16 + lr;
            float val = e[nt] * inv;
            ssp[nt] += val;
            ST[k * 64 + ((((p >> 3) ^ swz3(k))) << 3) + (p & 7)] = f2bf(val);
        }
    }
    #pragma unroll
    for (int nt = 0; nt < 4; ++nt) {
        float v = ssp[nt];
        v += __shfl_xor(v, 16);
        v += __shfl_xor(v, 32);
        if (lg == 0) ssumW[w * 64 + nt * 16 + lr] = v;
    }
    __syncthreads();

    if (tid < 64)
        ssumG[bs * 64 + tid] = ssumW[tid] + ssumW[64 + tid] + ssumW[128 + tid] + ssumW[192 + tid];

    // ---- phase 2: vlad_pos = simT x F_T via MFMA; wave w owns cluster-tile w ----
    f32x4 vac[8];
    #pragma unroll
    for (int dt = 0; dt < 8; ++dt) vac[dt] = (f32x4){0.f, 0.f, 0.f, 0.f};
    const int krow = 16 * w + lr;
    #pragma unroll
    for (int ks = 0; ks < 2; ++ks) {
        int cA = (ks * 4 + lg) ^ swz3(krow);
        short8 af = *(const short8*)(ST + krow * 64 + (cA << 3));
        #pragma unroll
        for (int dt = 0; dt < 8; ++dt) {
            int d  = dt * 16 + lr;
            int cB = (ks * 4 + lg) ^ swz3(d);
            short8 bf = *(const short8*)(FT + d * 64 + (cB << 3));
            vac[dt] = __builtin_amdgcn_mfma_f32_16x16x32_bf16(af, bf, vac[dt], 0, 0, 0);
        }
    }

    // ---- epilogue: write vlad_pos partial (no center term; reduce handles it) ----
    float* outp = partial + (size_t)bs * 8192;
    #pragma unroll
    for (int r = 0; r < 4; ++r) {
        int k = 16 * w + 4 * lg + r;
        #pragma unroll
        for (int dt = 0; dt < 8; ++dt)
            outp[k * 128 + dt * 16 + lr] = vac[dt][r];
    }
}

__global__ __launch_bounds__(256)
void netvlad_reduce(const float* __restrict__ partial,
                    const float* __restrict__ cent,
                    const float* __restrict__ ssumG,
                    float* __restrict__ vlad,
                    float* __restrict__ sqpart) {
    __shared__ float wsum[4];
    int idx = blockIdx.x * 256 + threadIdx.x;   // float4 id over (b, k, d4)
    int b   = idx >> 11;
    int rem = idx & 2047;
    int k   = rem >> 5;
    const float4* p4 = (const float4*)partial;
    float4 a = make_float4(0.f, 0.f, 0.f, 0.f);
    float  ss = 0.f;
    #pragma unroll
    for (int s = 0; s < SPLIT; ++s) {
        float4 v = p4[((size_t)(b * SPLIT + s)) * 2048 + rem];
        a.x += v.x; a.y += v.y; a.z += v.z; a.w += v.w;
        ss += ssumG[(b * SPLIT + s) * 64 + k];
    }
    float4 c4 = ((const float4*)cent)[b * 2048 + rem];
    a.x -= ss * c4.x; a.y -= ss * c4.y; a.z -= ss * c4.z; a.w -= ss * c4.w;
    ((float4*)vlad)[idx] = a;
    float sq = a.x * a.x + a.y * a.y + a.z * a.z + a.w * a.w;
    #pragma unroll
    for (int o = 32; o >= 1; o >>= 1) sq += __shfl_xor(sq, o);
    if ((threadIdx.x & 63) == 0) wsum[threadIdx.x >> 6] = sq;
    __syncthreads();
    if (threadIdx.x == 0) sqpart[blockIdx.x] = wsum[0] + wsum[1] + wsum[2] + wsum[3];
}

__global__ __launch_bounds__(256)
void netvlad_norm(const float* __restrict__ vlad,
                  const float* __restrict__ sqpart,
                  float* __restrict__ out) {
    const float4* sq4 = (const float4*)sqpart;
    float4 v = sq4[threadIdx.x & 63];
    float t = v.x + v.y + v.z + v.w;
    #pragma unroll
    for (int o = 32; o >= 1; o >>= 1) t += __shfl_xor(t, o);
    float inv = __builtin_amdgcn_rcpf(sqrtf(fmaxf(t, 1e-12f)));
    int idx = blockIdx.x * 256 + threadIdx.x;
    float4 x = ((const float4*)vlad)[idx];
    ((float4*)out)[idx] = make_float4(x.x * inv, x.y * inv, x.z * inv, x.w * inv);
}

extern "C" void kernel_launch(void* const* d_in, const int* in_sizes, int n_in,
                              void* d_out, int out_size, void* d_ws, size_t ws_size,
                              hipStream_t stream) {
    const float* feat = (const float*)d_in[0];   // (32,32,32,128)
    const float* cent = (const float*)d_in[1];   // (32,64,128)
    float* out = (float*)d_out;                  // (32,8192)

    char* ws = (char*)d_ws;
    const size_t partial_bytes = (size_t)NB * SPLIT * 64 * 128 * sizeof(float); // 16 MB
    const size_t vlad_bytes    = (size_t)NB * 64 * 128 * sizeof(float);         // 1 MB
    const size_t ssum_bytes    = (size_t)NB * SPLIT * 64 * sizeof(float);       // 128 KB
    float* partial = (float*)ws;
    float* vlad    = (float*)(ws + partial_bytes);
    float* ssumG   = (float*)(ws + partial_bytes + vlad_bytes);
    float* sqpart  = (float*)(ws + partial_bytes + vlad_bytes + ssum_bytes);    // 256 floats

    netvlad_main  <<<NB * SPLIT, 256, 0, stream>>>(feat, cent, partial, ssumG);
    netvlad_reduce<<<256, 256, 0, stream>>>(partial, cent, ssumG, vlad, sqpart);
    netvlad_norm  <<<256, 256, 0, stream>>>(vlad, sqpart, out);
}